// Round 3
// baseline (512.725 us; speedup 1.0000x reference)
//
#include <hip/hip_runtime.h>

// SAMMCodebook.encode, round 6: barrier-free inner loop. Wave-owned B staging
// (each wave global_load_lds's exactly the 128 codebook rows it consumes) with
// counted s_waitcnt vmcnt(8) — no per-K-step __syncthreads. Shared A staged in
// 128-elem chunks (block barrier only once per 4 K-steps). XOR-swizzled A and
// B tiles for conflict-free ds_read_b128; setprio(1) around the MFMA cluster;
// in-block exact fp32 fixup.
//
// z[n] = argmin_k (csq[k] - 2<h_n,c_k>). bf16 score error std ~0.1; DELTA=4
// (~40 sigma) margin guarantees the true argmin is among the candidates.

#define D_DIM 1024
#define K_CB  512
#define DELTA 4.0f
#define MAXC_IN 15            // stored "other" candidates; +1 best = 16 slots
#define FULLSCAN 0xFFFFu

typedef __attribute__((ext_vector_type(8))) short short8;
typedef __attribute__((ext_vector_type(4))) float floatx4;

// ws layout
#define WS_CBB  0ull           // 1 MB   cb bf16
#define WS_CSQ  1048576ull     // 2 KB   ||c||^2

typedef const unsigned int __attribute__((address_space(1)))* gaddr_t;
typedef unsigned int __attribute__((address_space(3)))* laddr_t;
static __device__ __forceinline__ void async_copy16(const void* g, void* l) {
    __builtin_amdgcn_global_load_lds((gaddr_t)g, (laddr_t)l, 16, 0, 0);
}

static __device__ __forceinline__ unsigned f2bf(float f) {
    unsigned u = __builtin_bit_cast(unsigned, f);
    return (u + 0x7FFFu + ((u >> 16) & 1u)) >> 16;   // round-nearest-even
}

// ---------------- cb fp32 -> bf16 + csq ----------------
__global__ __launch_bounds__(256)
void prep_kernel(const float* __restrict__ cb, unsigned short* __restrict__ cbb,
                 float* __restrict__ csq) {
    __shared__ float red[4];
    const int k = blockIdx.x, t = threadIdx.x;
    const float4 v = *(const float4*)(cb + (size_t)k * D_DIM + t * 4);
    uint2 u;
    u.x = f2bf(v.x) | (f2bf(v.y) << 16);
    u.y = f2bf(v.z) | (f2bf(v.w) << 16);
    *(uint2*)(cbb + (size_t)k * D_DIM + t * 4) = u;
    float s = v.x * v.x + v.y * v.y + v.z * v.z + v.w * v.w;
    #pragma unroll
    for (int off = 32; off > 0; off >>= 1) s += __shfl_down(s, off, 64);
    if ((t & 63) == 0) red[t >> 6] = s;
    __syncthreads();
    if (t == 0) csq[k] = red[0] + red[1] + red[2] + red[3];
}

// ---------------- coarse: 64x512 per block, barrier-free B pipeline ----------------
__global__ __launch_bounds__(256, 2)
void coarse_kernel(const float* __restrict__ h,
                   const unsigned short* __restrict__ cbb,
                   const float* __restrict__ csq,
                   const float* __restrict__ cb,
                   int* __restrict__ out) {
    // As = [64][128] bf16 chunk (16 KB, slot-swizzled), Bs = 2 x [512][32] bf16
    // (64 KB, wave-owned rows). Total 80 KB -> 2 blocks/CU.
    // Post-loop overlay: mval[64][129] f32 | mcol[64][129] i32 | ccnt | clist.
    __shared__ unsigned char smem[81920] __attribute__((aligned(16)));
    unsigned short* As = (unsigned short*)smem;               // shorts
    unsigned short* Bs = (unsigned short*)(smem + 16384);

    const int tid = threadIdx.x;
    const int w = tid >> 6, lane = tid & 63;
    const int l15 = lane & 15, kq = lane >> 4;
    const size_t row0 = (size_t)blockIdx.x * 64;
    const int wc_ = w * 128;                 // wave's 128-col range

    // B read swizzle (proven r5b): phys 16B-slot = kq ^ ((l15>>1)&3)
    const int qp8 = (kq ^ ((l15 >> 1) & 3)) * 8;

    // B staging, wave-owned: j-th global_load_lds covers rows w*128+j*16..+15
    // (lane -> row +lane>>2, phys slot lane&3). Global source pre-swizzled:
    // logical slot qsrc = (lane&3) ^ ((lane>>3)&3)  [= phys ^ ((row>>1)&3)].
    const int qsrc = (lane & 3) ^ ((lane >> 3) & 3);
    const int brow = w * 128 + (lane >> 2);
    const unsigned char* cbb_b = (const unsigned char*)cbb;
    const size_t bsrc_base = ((size_t)brow * D_DIM + qsrc * 8) * 2;   // bytes

    // A staging (per 128-elem chunk): thread t -> row ar=t>>2, elems (t&3)*32..
    const int ar = tid >> 2, aq4 = (tid & 3) * 4;
    const float* gA = h + (row0 + ar) * D_DIM + (tid & 3) * 32;
    // A read swizzle: phys slot = (i*4+kq) ^ (row&7), row&7 == l15&7
    const int aswz = l15 & 7;

    floatx4 acc[4][8];
    #pragma unroll
    for (int i = 0; i < 4; ++i)
        #pragma unroll
        for (int j = 0; j < 8; ++j) acc[i][j] = (floatx4){0.f, 0.f, 0.f, 0.f};

#define ISSUE_B(dkn, par) \
    _Pragma("unroll") \
    for (int j = 0; j < 8; ++j) \
        async_copy16(cbb_b + bsrc_base + (size_t)j * (16 * D_DIM * 2) + (size_t)(dkn) * 2, \
                     Bs + (par) * 16384 + (w * 128 + j * 16) * 32);

#define STAGE_A(cc) do { \
    floatx4 av[8]; \
    _Pragma("unroll") \
    for (int k = 0; k < 8; ++k) \
        av[k] = __builtin_nontemporal_load((const floatx4*)(gA + (cc) * 128 + k * 4)); \
    _Pragma("unroll") \
    for (int j = 0; j < 4; ++j) { \
        uint4 u; \
        u.x = f2bf(av[2 * j].x)     | (f2bf(av[2 * j].y) << 16); \
        u.y = f2bf(av[2 * j].z)     | (f2bf(av[2 * j].w) << 16); \
        u.z = f2bf(av[2 * j + 1].x) | (f2bf(av[2 * j + 1].y) << 16); \
        u.w = f2bf(av[2 * j + 1].z) | (f2bf(av[2 * j + 1].w) << 16); \
        const int ps = (aq4 + j) ^ (ar & 7); \
        *(uint4*)(As + ar * 128 + ps * 8) = u; \
    } \
} while (0)

// One K-step: issue next B batch (wave-own), counted vmcnt(8) so the new batch
// stays in flight across the MFMA cluster; vmcnt(0) only at the very last step.
#define INNER_STEP(ii, PF) do { \
    if (PF) { \
        ISSUE_B((c4 + (ii) + 1) * 32, ((ii) + 1) & 1); \
        asm volatile("s_waitcnt vmcnt(8)" ::: "memory"); \
    } else { \
        asm volatile("s_waitcnt vmcnt(0)" ::: "memory"); \
    } \
    __builtin_amdgcn_sched_barrier(0); \
    short8 a[4], b[8]; \
    _Pragma("unroll") \
    for (int rt = 0; rt < 4; ++rt) \
        a[rt] = *(const short8*)(As + (rt * 16 + l15) * 128 + ((((ii) * 4 + kq)) ^ aswz) * 8); \
    _Pragma("unroll") \
    for (int ct = 0; ct < 8; ++ct) \
        b[ct] = *(const short8*)(Bs + ((ii) & 1) * 16384 + (wc_ + ct * 16 + l15) * 32 + qp8); \
    __builtin_amdgcn_s_setprio(1); \
    _Pragma("unroll") \
    for (int rt = 0; rt < 4; ++rt) \
        _Pragma("unroll") \
        for (int ct = 0; ct < 8; ++ct) \
            acc[rt][ct] = __builtin_amdgcn_mfma_f32_16x16x32_bf16( \
                a[rt], b[ct], acc[rt][ct], 0, 0, 0); \
    __builtin_amdgcn_s_setprio(0); \
} while (0)

    // prologue: B(step 0) into buffer 0 (drained by the first __syncthreads)
    ISSUE_B(0, 0);

    for (int c = 0; c < 7; ++c) {
        const int c4 = c * 4;
        STAGE_A(c);
        __syncthreads();     // A chunk visible; also drains this wave's B loads
        INNER_STEP(0, true);
        INNER_STEP(1, true);
        INNER_STEP(2, true);
        INNER_STEP(3, true);
        __syncthreads();     // all waves done reading As before next overwrite
    }
    {
        const int c4 = 28;
        STAGE_A(7);
        __syncthreads();
        INNER_STEP(0, true);
        INNER_STEP(1, true);
        INNER_STEP(2, true);
        INNER_STEP(3, false);
    }

#undef INNER_STEP
#undef STAGE_A
#undef ISSUE_B

    // ---- fold: per-lane top-2 per row-reg (cell = 8 cols) ----
    float k1[16], k2[16];
    unsigned cpk[16];
    #pragma unroll
    for (int i = 0; i < 16; ++i) { k1[i] = 3.4e38f; k2[i] = 3.4e38f; cpk[i] = 0; }
    #pragma unroll
    for (int ct = 0; ct < 8; ++ct) {
        const int col = wc_ + ct * 16 + l15;
        const float cq = csq[col];
        #pragma unroll
        for (int rt = 0; rt < 4; ++rt)
            #pragma unroll
            for (int reg = 0; reg < 4; ++reg) {
                const float s = fmaf(-2.0f, acc[rt][ct][reg], cq);
                const int ri = rt * 4 + reg;
                if (s < k1[ri]) {
                    k2[ri] = k1[ri]; k1[ri] = s;
                    cpk[ri] = (cpk[ri] << 16) | (unsigned)col;
                } else if (s < k2[ri]) {
                    k2[ri] = s;
                    cpk[ri] = (cpk[ri] & 0xFFFFu) | ((unsigned)col << 16);
                }
            }
    }

    // ---- merge: 128 entries per row via LDS (stride 129: conflict-free scan) ----
    float* mval = (float*)smem;                        // [64][129]
    int*   mcol = (int*)(smem + 33024);                // [64][129]
    unsigned short* ccnt  = (unsigned short*)(smem + 66048);   // [64]
    unsigned short* clist = (unsigned short*)(smem + 66176);   // [64][16]
    __syncthreads();
    #pragma unroll
    for (int rt = 0; rt < 4; ++rt)
        #pragma unroll
        for (int reg = 0; reg < 4; ++reg) {
            const int ri = rt * 4 + reg;
            const int r = rt * 16 + kq * 4 + reg;
            const int e = (w * 16 + l15) * 2;
            mval[r * 129 + e] = k1[ri];
            mcol[r * 129 + e] = (int)(cpk[ri] & 0xFFFFu);
            mval[r * 129 + e + 1] = k2[ri];
            mcol[r * 129 + e + 1] = (int)(cpk[ri] >> 16);
        }
    __syncthreads();

    // ---- decide: best + candidate list per row ----
    if (tid < 64) {
        const int r = tid;
        float bv = mval[r * 129]; int bc = mcol[r * 129];
        for (int e = 1; e < 128; ++e) {
            const float v = mval[r * 129 + e];
            const int   c = mcol[r * 129 + e];
            if (v < bv || (v == bv && c < bc)) { bv = v; bc = c; }
        }
        const float thr = bv + DELTA;
        int others = 0;
        for (int e = 0; e < 128; ++e) {
            const float v = mval[r * 129 + e];
            const int   c = mcol[r * 129 + e];
            if (v < thr && c != bc) {
                if (others < MAXC_IN) clist[r * 16 + 1 + others] = (unsigned short)c;
                ++others;
            }
        }
        if (others == 0) {
            out[row0 + r] = bc;          // unambiguous: approx winner is exact
            ccnt[r] = 0;
        } else if (others <= MAXC_IN) {
            clist[r * 16] = (unsigned short)bc;
            ccnt[r] = (unsigned short)(others + 1);
        } else {
            ccnt[r] = (unsigned short)FULLSCAN;
        }
    }
    __syncthreads();

    // ---- in-block exact fp32 fixup: one wave per ambiguous row ----
    for (int r = w; r < 64; r += 4) {
        const unsigned cnt = ccnt[r];
        if (cnt == 0) continue;
        const size_t grow = row0 + r;
        const float* hrow = h + grow * D_DIM;
        float4 hv[4];
        #pragma unroll
        for (int j = 0; j < 4; ++j)
            hv[j] = *(const float4*)(hrow + j * 256 + lane * 4);
        float bs = 3.4e38f; int bc = 0x7fffffff;
        const bool full = (cnt == FULLSCAN);
        const int total = full ? K_CB : (int)cnt;
        for (int i = 0; i < total; ++i) {
            const int c = full ? i : (int)clist[r * 16 + i];
            const float* crow = cb + (size_t)c * D_DIM;
            float d = 0.0f;
            #pragma unroll
            for (int j = 0; j < 4; ++j) {
                const float4 cv = *(const float4*)(crow + j * 256 + lane * 4);
                d = fmaf(hv[j].x, cv.x, d);
                d = fmaf(hv[j].y, cv.y, d);
                d = fmaf(hv[j].z, cv.z, d);
                d = fmaf(hv[j].w, cv.w, d);
            }
            #pragma unroll
            for (int off = 32; off > 0; off >>= 1) d += __shfl_down(d, off, 64);
            d = __shfl(d, 0, 64);
            const float sc = fmaf(-2.0f, d, csq[c]);
            if (sc < bs || (sc == bs && c < bc)) { bs = sc; bc = c; }
        }
        if (lane == 0) out[grow] = bc;
    }
}

extern "C" void kernel_launch(void* const* d_in, const int* in_sizes, int n_in,
                              void* d_out, int out_size, void* d_ws, size_t ws_size,
                              hipStream_t stream) {
    const float* h  = (const float*)d_in[0];
    const float* cb = (const float*)d_in[1];
    int* out = (int*)d_out;
    unsigned char* ws = (unsigned char*)d_ws;
    const int nrows = in_sizes[0] / D_DIM;   // 65536

    unsigned short* cbb = (unsigned short*)(ws + WS_CBB);
    float* csq = (float*)(ws + WS_CSQ);

    prep_kernel<<<dim3(K_CB), dim3(256), 0, stream>>>(cb, cbb, csq);
    coarse_kernel<<<dim3(nrows / 64), dim3(256), 0, stream>>>(
        h, cbb, csq, cb, out);
}

// Round 4
// 462.992 us; speedup vs baseline: 1.1074x; 1.1074x over previous
//
#include <hip/hip_runtime.h>

// SAMMCodebook.encode, round 7: never-drain K-loop. r5b geometry/swizzles
// (A 2x[64][32] bf16 LDS, wave-owned B 2x[512][32] bf16 LDS) with a counted
// vmcnt schedule: per step issue A(s+1) reg loads + B(s+1) global_load_lds,
// wait vmcnt(10) (drains only B(s)), ds_read + 32 MFMA, wait vmcnt(8), cvt +
// ds_write A(s+1), lgkmcnt(0), raw s_barrier. vmcnt never hits 0 in the loop
// -> ~10 KB/wave permanently in flight -> HBM latency amortized.
//
// z[n] = argmin_k (csq[k] - 2<h_n,c_k>). bf16 score error std ~0.1; DELTA=4
// (~40 sigma) margin guarantees the true argmin is among the candidates.

#define D_DIM 1024
#define K_CB  512
#define DELTA 4.0f
#define MAXC_IN 15            // stored "other" candidates; +1 best = 16 slots
#define FULLSCAN 0xFFFFu

typedef __attribute__((ext_vector_type(8))) short short8;
typedef __attribute__((ext_vector_type(4))) float floatx4;

// ws layout
#define WS_CBB  0ull           // 1 MB   cb bf16
#define WS_CSQ  1048576ull     // 2 KB   ||c||^2

typedef const unsigned int __attribute__((address_space(1)))* gaddr_t;
typedef unsigned int __attribute__((address_space(3)))* laddr_t;
static __device__ __forceinline__ void async_copy16(const void* g, void* l) {
    __builtin_amdgcn_global_load_lds((gaddr_t)g, (laddr_t)l, 16, 0, 0);
}

static __device__ __forceinline__ unsigned f2bf(float f) {
    unsigned u = __builtin_bit_cast(unsigned, f);
    return (u + 0x7FFFu + ((u >> 16) & 1u)) >> 16;   // round-nearest-even
}

// ---------------- cb fp32 -> bf16 + csq ----------------
__global__ __launch_bounds__(256)
void prep_kernel(const float* __restrict__ cb, unsigned short* __restrict__ cbb,
                 float* __restrict__ csq) {
    __shared__ float red[4];
    const int k = blockIdx.x, t = threadIdx.x;
    const float4 v = *(const float4*)(cb + (size_t)k * D_DIM + t * 4);
    uint2 u;
    u.x = f2bf(v.x) | (f2bf(v.y) << 16);
    u.y = f2bf(v.z) | (f2bf(v.w) << 16);
    *(uint2*)(cbb + (size_t)k * D_DIM + t * 4) = u;
    float s = v.x * v.x + v.y * v.y + v.z * v.z + v.w * v.w;
    #pragma unroll
    for (int off = 32; off > 0; off >>= 1) s += __shfl_down(s, off, 64);
    if ((t & 63) == 0) red[t >> 6] = s;
    __syncthreads();
    if (t == 0) csq[k] = red[0] + red[1] + red[2] + red[3];
}

// ---------------- coarse: 64x512 per block, counted-vmcnt pipeline ----------------
__global__ __launch_bounds__(256, 2)
void coarse_kernel(const float* __restrict__ h,
                   const unsigned short* __restrict__ cbb,
                   const float* __restrict__ csq,
                   const float* __restrict__ cb,
                   int* __restrict__ out) {
    // As = 2 x [64][32] bf16 (8 KB), Bs = 2 x [512][32] bf16 (64 KB) = 72 KB.
    // Post-loop overlay: mval[64][129] f32 | mcol[64][129] i32 | ccnt | clist.
    __shared__ unsigned char smem[73728] __attribute__((aligned(16)));
    unsigned short* As = (unsigned short*)smem;               // shorts
    unsigned short* Bs = (unsigned short*)(smem + 8192);

    const int tid = threadIdx.x;
    const int w = tid >> 6, lane = tid & 63;
    const int l15 = lane & 15, kq = lane >> 4;
    const size_t row0 = (size_t)blockIdx.x * 64;
    const int wc_ = w * 128;                 // wave's 128-col range

    // read-side swizzled 16B-slot offset (r5b-proven), same for A and B
    const int qp8 = (kq ^ ((l15 >> 1) & 3)) * 8;

    // A staging: thread -> row ar=tid>>2, logical slot aql=tid&3 (8 fp32)
    const int ar = tid >> 2, aql = tid & 3;
    const float* gA = h + (row0 + ar) * D_DIM + aql * 8;
    const int awoff = ar * 32 + (aql ^ ((ar >> 1) & 3)) * 8;  // swizzled write

    // B staging, wave-owned (r6-proven): inst j covers rows w*128+j*16..+15;
    // lane -> row +(lane>>2), phys slot lane&3; pre-swizzled global source.
    const int qsrc = (lane & 3) ^ ((lane >> 3) & 3);
    const int brow = w * 128 + (lane >> 2);
    const unsigned char* cbb_b = (const unsigned char*)cbb;
    const size_t bsrc_base = ((size_t)brow * D_DIM + qsrc * 8) * 2;   // bytes

    floatx4 acc[4][8];
    #pragma unroll
    for (int i = 0; i < 4; ++i)
        #pragma unroll
        for (int j = 0; j < 8; ++j) acc[i][j] = (floatx4){0.f, 0.f, 0.f, 0.f};

    float4 va0, va1;

#define ISSUE_B(dkn, par) \
    _Pragma("unroll") \
    for (int j = 0; j < 8; ++j) \
        async_copy16(cbb_b + bsrc_base + (size_t)j * (16 * D_DIM * 2) + (size_t)(dkn) * 2, \
                     Bs + (par) * 16384 + (w * 128 + j * 16) * 32);

#define LOAD_A(dkn) do { \
    va0 = *(const float4*)(gA + (dkn)); \
    va1 = *(const float4*)(gA + (dkn) + 4); \
} while (0)

#define PUB_A(par) do { \
    uint4 u; \
    u.x = f2bf(va0.x) | (f2bf(va0.y) << 16); \
    u.y = f2bf(va0.z) | (f2bf(va0.w) << 16); \
    u.z = f2bf(va1.x) | (f2bf(va1.y) << 16); \
    u.w = f2bf(va1.z) | (f2bf(va1.w) << 16); \
    *(uint4*)(As + (par) * 2048 + awoff) = u; \
} while (0)

    // ---- prologue: stage step 0 (A regs + B lds), publish A(0) ----
    LOAD_A(0);
    ISSUE_B(0, 0);
    asm volatile("s_waitcnt vmcnt(8)" ::: "memory");   // A(0) regs done
    __builtin_amdgcn_sched_barrier(0);
    PUB_A(0);
    asm volatile("s_waitcnt lgkmcnt(0)" ::: "memory"); // A(0) write visible
    __builtin_amdgcn_s_barrier();
    __builtin_amdgcn_sched_barrier(0);
    // entering step 0: exactly 8 outstanding (B(0))

#define STEP(p, s, LAST) do { \
    if (!(LAST)) { \
        LOAD_A(((s) + 1) * 32); \
        ISSUE_B(((s) + 1) * 32, (p) ^ 1); \
        asm volatile("s_waitcnt vmcnt(10)" ::: "memory");  /* B(s) landed */ \
    } else { \
        asm volatile("s_waitcnt vmcnt(0)" ::: "memory"); \
    } \
    __builtin_amdgcn_sched_barrier(0); \
    short8 a[4], b[8]; \
    _Pragma("unroll") \
    for (int rt = 0; rt < 4; ++rt) \
        a[rt] = *(const short8*)(As + (p) * 2048 + (rt * 16 + l15) * 32 + qp8); \
    _Pragma("unroll") \
    for (int ct = 0; ct < 8; ++ct) \
        b[ct] = *(const short8*)(Bs + (p) * 16384 + (wc_ + ct * 16 + l15) * 32 + qp8); \
    __builtin_amdgcn_s_setprio(1); \
    _Pragma("unroll") \
    for (int rt = 0; rt < 4; ++rt) \
        _Pragma("unroll") \
        for (int ct = 0; ct < 8; ++ct) \
            acc[rt][ct] = __builtin_amdgcn_mfma_f32_16x16x32_bf16( \
                a[rt], b[ct], acc[rt][ct], 0, 0, 0); \
    __builtin_amdgcn_s_setprio(0); \
    if (!(LAST)) { \
        asm volatile("s_waitcnt vmcnt(8)" ::: "memory");   /* A(s+1) regs */ \
        __builtin_amdgcn_sched_barrier(0); \
        PUB_A((p) ^ 1); \
    } \
    asm volatile("s_waitcnt lgkmcnt(0)" ::: "memory");     /* A write visible */ \
    __builtin_amdgcn_s_barrier(); \
    __builtin_amdgcn_sched_barrier(0); \
} while (0)

    for (int s2 = 0; s2 < 15; ++s2) {
        STEP(0, 2 * s2, false);
        STEP(1, 2 * s2 + 1, false);
    }
    STEP(0, 30, false);
    STEP(1, 31, true);

#undef STEP
#undef PUB_A
#undef LOAD_A
#undef ISSUE_B

    // ---- fold: per-lane top-2 per row-reg (cell = 8 cols) ----
    float k1[16], k2[16];
    unsigned cpk[16];
    #pragma unroll
    for (int i = 0; i < 16; ++i) { k1[i] = 3.4e38f; k2[i] = 3.4e38f; cpk[i] = 0; }
    #pragma unroll
    for (int ct = 0; ct < 8; ++ct) {
        const int col = wc_ + ct * 16 + l15;
        const float cq = csq[col];
        #pragma unroll
        for (int rt = 0; rt < 4; ++rt)
            #pragma unroll
            for (int reg = 0; reg < 4; ++reg) {
                const float s = fmaf(-2.0f, acc[rt][ct][reg], cq);
                const int ri = rt * 4 + reg;
                if (s < k1[ri]) {
                    k2[ri] = k1[ri]; k1[ri] = s;
                    cpk[ri] = (cpk[ri] << 16) | (unsigned)col;
                } else if (s < k2[ri]) {
                    k2[ri] = s;
                    cpk[ri] = (cpk[ri] & 0xFFFFu) | ((unsigned)col << 16);
                }
            }
    }

    // ---- merge: 128 entries per row via LDS (stride 129: conflict-free scan) ----
    float* mval = (float*)smem;                        // [64][129]
    int*   mcol = (int*)(smem + 33024);                // [64][129]
    unsigned short* ccnt  = (unsigned short*)(smem + 66048);   // [64]
    unsigned short* clist = (unsigned short*)(smem + 66176);   // [64][16]
    __syncthreads();
    #pragma unroll
    for (int rt = 0; rt < 4; ++rt)
        #pragma unroll
        for (int reg = 0; reg < 4; ++reg) {
            const int ri = rt * 4 + reg;
            const int r = rt * 16 + kq * 4 + reg;
            const int e = (w * 16 + l15) * 2;
            mval[r * 129 + e] = k1[ri];
            mcol[r * 129 + e] = (int)(cpk[ri] & 0xFFFFu);
            mval[r * 129 + e + 1] = k2[ri];
            mcol[r * 129 + e + 1] = (int)(cpk[ri] >> 16);
        }
    __syncthreads();

    // ---- decide: best + candidate list per row ----
    if (tid < 64) {
        const int r = tid;
        float bv = mval[r * 129]; int bc = mcol[r * 129];
        for (int e = 1; e < 128; ++e) {
            const float v = mval[r * 129 + e];
            const int   c = mcol[r * 129 + e];
            if (v < bv || (v == bv && c < bc)) { bv = v; bc = c; }
        }
        const float thr = bv + DELTA;
        int others = 0;
        for (int e = 0; e < 128; ++e) {
            const float v = mval[r * 129 + e];
            const int   c = mcol[r * 129 + e];
            if (v < thr && c != bc) {
                if (others < MAXC_IN) clist[r * 16 + 1 + others] = (unsigned short)c;
                ++others;
            }
        }
        if (others == 0) {
            out[row0 + r] = bc;          // unambiguous: approx winner is exact
            ccnt[r] = 0;
        } else if (others <= MAXC_IN) {
            clist[r * 16] = (unsigned short)bc;
            ccnt[r] = (unsigned short)(others + 1);
        } else {
            ccnt[r] = (unsigned short)FULLSCAN;
        }
    }
    __syncthreads();

    // ---- in-block exact fp32 fixup: one wave per ambiguous row ----
    for (int r = w; r < 64; r += 4) {
        const unsigned cnt = ccnt[r];
        if (cnt == 0) continue;
        const size_t grow = row0 + r;
        const float* hrow = h + grow * D_DIM;
        float4 hv[4];
        #pragma unroll
        for (int j = 0; j < 4; ++j)
            hv[j] = *(const float4*)(hrow + j * 256 + lane * 4);
        float bs = 3.4e38f; int bc = 0x7fffffff;
        const bool full = (cnt == FULLSCAN);
        const int total = full ? K_CB : (int)cnt;
        for (int i = 0; i < total; ++i) {
            const int c = full ? i : (int)clist[r * 16 + i];
            const float* crow = cb + (size_t)c * D_DIM;
            float d = 0.0f;
            #pragma unroll
            for (int j = 0; j < 4; ++j) {
                const float4 cv = *(const float4*)(crow + j * 256 + lane * 4);
                d = fmaf(hv[j].x, cv.x, d);
                d = fmaf(hv[j].y, cv.y, d);
                d = fmaf(hv[j].z, cv.z, d);
                d = fmaf(hv[j].w, cv.w, d);
            }
            #pragma unroll
            for (int off = 32; off > 0; off >>= 1) d += __shfl_down(d, off, 64);
            d = __shfl(d, 0, 64);
            const float sc = fmaf(-2.0f, d, csq[c]);
            if (sc < bs || (sc == bs && c < bc)) { bs = sc; bc = c; }
        }
        if (lane == 0) out[grow] = bc;
    }
}

extern "C" void kernel_launch(void* const* d_in, const int* in_sizes, int n_in,
                              void* d_out, int out_size, void* d_ws, size_t ws_size,
                              hipStream_t stream) {
    const float* h  = (const float*)d_in[0];
    const float* cb = (const float*)d_in[1];
    int* out = (int*)d_out;
    unsigned char* ws = (unsigned char*)d_ws;
    const int nrows = in_sizes[0] / D_DIM;   // 65536

    unsigned short* cbb = (unsigned short*)(ws + WS_CBB);
    float* csq = (float*)(ws + WS_CSQ);

    prep_kernel<<<dim3(K_CB), dim3(256), 0, stream>>>(cb, cbb, csq);
    coarse_kernel<<<dim3(nrows / 64), dim3(256), 0, stream>>>(
        h, cbb, csq, cb, out);
}